// Round 1
// baseline (564.098 us; speedup 1.0000x reference)
//
#include <hip/hip_runtime.h>
#include <math.h>

// Problem constants
#define BB 8
#define CC 256
#define NN 1024     // H*W
#define HEADS 8
#define HDIM 32
#define NGRP 8

// ---------------------------------------------------------------------------
// Kernel 1: GroupNorm. One block per (b, group). Group = 32 contiguous
// channels = 32768 contiguous floats. 1024 threads, 8 float4 each, held in
// registers across the reduce so the normalize pass re-reads nothing.
// ---------------------------------------------------------------------------
__global__ __launch_bounds__(1024) void gn_kernel(
    const float* __restrict__ x, const float* __restrict__ gns,
    const float* __restrict__ gnb, float* __restrict__ h)
{
  const int t = threadIdx.x;
  const int b = blockIdx.x >> 3, g = blockIdx.x & 7;
  const size_t base4 = (((size_t)b * CC + (size_t)g * 32) * NN) >> 2;
  const float4* x4 = (const float4*)x + base4;
  float4* h4 = (float4*)h + base4;

  float4 r[8];
  float s = 0.f, ss = 0.f;
#pragma unroll
  for (int j = 0; j < 8; ++j) {
    r[j] = x4[t + j * 1024];
    s  += r[j].x + r[j].y + r[j].z + r[j].w;
    ss += r[j].x * r[j].x + r[j].y * r[j].y + r[j].z * r[j].z + r[j].w * r[j].w;
  }
#pragma unroll
  for (int off = 32; off > 0; off >>= 1) {
    s  += __shfl_down(s, off);
    ss += __shfl_down(ss, off);
  }
  __shared__ float rs[16], rss[16];
  __shared__ float smean, srstd;
  const int wid = t >> 6, lane = t & 63;
  if (lane == 0) { rs[wid] = s; rss[wid] = ss; }
  __syncthreads();
  if (t == 0) {
    float S = 0.f, SS = 0.f;
    for (int i = 0; i < 16; ++i) { S += rs[i]; SS += rss[i]; }
    const float mean = S * (1.f / 32768.f);
    const float var = SS * (1.f / 32768.f) - mean * mean;
    smean = mean;
    srstd = rsqrtf(var + 1e-5f);
  }
  __syncthreads();
  const float mean = smean, rstd = srstd;
#pragma unroll
  for (int j = 0; j < 8; ++j) {
    const int c = g * 32 + (t >> 8) + 4 * j;
    const float sc = gns[c] * rstd;
    const float bi = gnb[c];
    float4 o;
    o.x = (r[j].x - mean) * sc + bi;
    o.y = (r[j].y - mean) * sc + bi;
    o.z = (r[j].z - mean) * sc + bi;
    o.w = (r[j].w - mean) * sc + bi;
    h4[t + j * 1024] = o;
  }
}

// ---------------------------------------------------------------------------
// Kernel 2/4: 1x1 conv = GEMM  Y[b,o,n] = sum_k W[o,k] X[b,k,n] + bias[o]
// (+ optional residual R). 64x64 tile, BK=32, 256 threads, 4x4 per thread.
// LDS rows padded to 68 floats (272B, 16B-aligned) for b128 reads.
// ---------------------------------------------------------------------------
__global__ __launch_bounds__(256) void conv1x1_kernel(
    const float* __restrict__ W, const float* __restrict__ bias,
    const float* __restrict__ X, const float* __restrict__ R,
    float* __restrict__ Y, int O)
{
  const int t = threadIdx.x;
  const int tx = t & 15, ty = t >> 4;
  const int b = blockIdx.z;
  const int o0 = blockIdx.y << 6, n0 = blockIdx.x << 6;
  __shared__ float As[32][68];  // [k][o]
  __shared__ float Bs[32][68];  // [k][n]
  float acc[4][4] = {};
  const float* Xb = X + (size_t)b * CC * NN;

  for (int k0 = 0; k0 < 256; k0 += 32) {
#pragma unroll
    for (int l = 0; l < 2; ++l) {
      const int fi = t + (l << 8);  // 0..511
      const int o = fi >> 3, kq = fi & 7;
      const float4 w4 = *(const float4*)(W + (size_t)(o0 + o) * 256 + k0 + kq * 4);
      As[kq * 4 + 0][o] = w4.x;
      As[kq * 4 + 1][o] = w4.y;
      As[kq * 4 + 2][o] = w4.z;
      As[kq * 4 + 3][o] = w4.w;
      const int k = fi >> 4, nq = fi & 15;
      *(float4*)(&Bs[k][nq * 4]) =
          *(const float4*)(Xb + (size_t)(k0 + k) * NN + n0 + nq * 4);
    }
    __syncthreads();
#pragma unroll
    for (int k = 0; k < 32; ++k) {
      const float4 a  = *(const float4*)(&As[k][ty * 4]);
      const float4 bv = *(const float4*)(&Bs[k][tx * 4]);
      acc[0][0] += a.x * bv.x; acc[0][1] += a.x * bv.y; acc[0][2] += a.x * bv.z; acc[0][3] += a.x * bv.w;
      acc[1][0] += a.y * bv.x; acc[1][1] += a.y * bv.y; acc[1][2] += a.y * bv.z; acc[1][3] += a.y * bv.w;
      acc[2][0] += a.z * bv.x; acc[2][1] += a.z * bv.y; acc[2][2] += a.z * bv.z; acc[2][3] += a.z * bv.w;
      acc[3][0] += a.w * bv.x; acc[3][1] += a.w * bv.y; acc[3][2] += a.w * bv.z; acc[3][3] += a.w * bv.w;
    }
    __syncthreads();
  }
#pragma unroll
  for (int i = 0; i < 4; ++i) {
    const int o = o0 + ty * 4 + i;
    const float bi = bias[o];
    float4 v;
    v.x = acc[i][0] + bi; v.y = acc[i][1] + bi;
    v.z = acc[i][2] + bi; v.w = acc[i][3] + bi;
    const size_t idx = ((size_t)b * O + o) * NN + n0 + tx * 4;
    if (R) {
      const float4 r4 = *(const float4*)(R + idx);
      v.x += r4.x; v.y += r4.y; v.z += r4.z; v.w += r4.w;
    }
    *(float4*)(Y + idx) = v;
  }
}

// ---------------------------------------------------------------------------
// Kernel 3: flash-style attention. Block = 128 threads, each owns 2 query
// rows (amortizes LDS broadcast: each b128 K/V read feeds 8 FMA). Grid
// (4 query tiles, 64 b*h). Online softmax, acc in registers.
// ---------------------------------------------------------------------------
__global__ __launch_bounds__(128) void attn_kernel(
    const float* __restrict__ qkv, float* __restrict__ ao)
{
  const int t = threadIdx.x;
  const int bh = blockIdx.y;
  const int b = bh >> 3, hh = bh & 7;
  const int n0 = blockIdx.x << 8;
  const float* Q = qkv + ((size_t)b * 768 + hh * 32) * NN;
  const float* K = Q + 256 * NN;
  const float* V = Q + 512 * NN;
  __shared__ float Ks[32][20];  // [d][m], 16 keys, pad->20 (80B rows, aligned)
  __shared__ float Vs[16][36];  // [m][d], pad->36 (144B rows, aligned)

  const int na = n0 + t, nb = n0 + 128 + t;
  float qa[32], qb[32], aa[32] = {}, ab[32] = {};
  const float sc = 0.17677669529663689f;  // 1/sqrt(32)
#pragma unroll
  for (int d = 0; d < 32; ++d) {
    qa[d] = Q[d * NN + na] * sc;
    qb[d] = Q[d * NN + nb] * sc;
  }
  float ma = -1e30f, mb = -1e30f, la = 0.f, lb = 0.f;

  for (int m0 = 0; m0 < NN; m0 += 16) {
    __syncthreads();
    {
      const int d = t >> 2, mq = t & 3;
      const float4 k4 = *(const float4*)(K + (size_t)d * NN + m0 + mq * 4);
      *(float4*)(&Ks[d][mq * 4]) = k4;
      const float4 v4 = *(const float4*)(V + (size_t)d * NN + m0 + mq * 4);
      Vs[mq * 4 + 0][d] = v4.x;
      Vs[mq * 4 + 1][d] = v4.y;
      Vs[mq * 4 + 2][d] = v4.z;
      Vs[mq * 4 + 3][d] = v4.w;
    }
    __syncthreads();

    float sa[16], sb[16];
#pragma unroll
    for (int m = 0; m < 16; ++m) { sa[m] = 0.f; sb[m] = 0.f; }
#pragma unroll
    for (int d = 0; d < 32; ++d) {
      const float qda = qa[d], qdb = qb[d];
#pragma unroll
      for (int mq = 0; mq < 4; ++mq) {
        const float4 kv = *(const float4*)(&Ks[d][mq * 4]);
        sa[mq * 4 + 0] += qda * kv.x; sa[mq * 4 + 1] += qda * kv.y;
        sa[mq * 4 + 2] += qda * kv.z; sa[mq * 4 + 3] += qda * kv.w;
        sb[mq * 4 + 0] += qdb * kv.x; sb[mq * 4 + 1] += qdb * kv.y;
        sb[mq * 4 + 2] += qdb * kv.z; sb[mq * 4 + 3] += qdb * kv.w;
      }
    }
    float pma = sa[0], pmb = sb[0];
#pragma unroll
    for (int m = 1; m < 16; ++m) {
      pma = fmaxf(pma, sa[m]);
      pmb = fmaxf(pmb, sb[m]);
    }
    const float mna = fmaxf(ma, pma), mnb = fmaxf(mb, pmb);
    const float ca = __expf(ma - mna), cb = __expf(mb - mnb);
    ma = mna; mb = mnb;
    la *= ca; lb *= cb;
#pragma unroll
    for (int d = 0; d < 32; ++d) { aa[d] *= ca; ab[d] *= cb; }
#pragma unroll
    for (int m = 0; m < 16; ++m) {
      const float pa = __expf(sa[m] - ma), pb = __expf(sb[m] - mb);
      la += pa; lb += pb;
#pragma unroll
      for (int dq = 0; dq < 8; ++dq) {
        const float4 vv = *(const float4*)(&Vs[m][dq * 4]);
        aa[dq * 4 + 0] += pa * vv.x; aa[dq * 4 + 1] += pa * vv.y;
        aa[dq * 4 + 2] += pa * vv.z; aa[dq * 4 + 3] += pa * vv.w;
        ab[dq * 4 + 0] += pb * vv.x; ab[dq * 4 + 1] += pb * vv.y;
        ab[dq * 4 + 2] += pb * vv.z; ab[dq * 4 + 3] += pb * vv.w;
      }
    }
  }
  const float ra = 1.f / la, rb = 1.f / lb;
  float* aob = ao + ((size_t)b * CC + hh * 32) * NN;
#pragma unroll
  for (int d = 0; d < 32; ++d) {
    aob[(size_t)d * NN + na] = aa[d] * ra;
    aob[(size_t)d * NN + nb] = ab[d] * rb;
  }
}

// ---------------------------------------------------------------------------
// Launch: ws layout (floats): h[2M] | qkv[6M] | attn_out[2M]  = 40 MB total
// ---------------------------------------------------------------------------
extern "C" void kernel_launch(void* const* d_in, const int* in_sizes, int n_in,
                              void* d_out, int out_size, void* d_ws, size_t ws_size,
                              hipStream_t stream)
{
  const float* x    = (const float*)d_in[0];
  const float* gns  = (const float*)d_in[1];
  const float* gnb  = (const float*)d_in[2];
  const float* wqkv = (const float*)d_in[3];
  const float* bqkv = (const float*)d_in[4];
  const float* wout = (const float*)d_in[5];
  const float* bout = (const float*)d_in[6];
  float* out = (float*)d_out;

  float* h   = (float*)d_ws;                       // 2,097,152 floats
  float* qkv = h + (size_t)BB * CC * NN;           // 6,291,456 floats
  float* ao  = qkv + (size_t)BB * 3 * CC * NN;     // 2,097,152 floats

  gn_kernel<<<dim3(64), dim3(1024), 0, stream>>>(x, gns, gnb, h);
  conv1x1_kernel<<<dim3(16, 12, 8), dim3(256), 0, stream>>>(wqkv, bqkv, h, nullptr, qkv, 768);
  attn_kernel<<<dim3(4, 64), dim3(128), 0, stream>>>(qkv, ao);
  conv1x1_kernel<<<dim3(16, 4, 8), dim3(256), 0, stream>>>(wout, bout, ao, x, out, 256);
}

// Round 2
// 184.598 us; speedup vs baseline: 3.0558x; 3.0558x over previous
//
#include <hip/hip_runtime.h>
#include <math.h>

// Problem constants
#define BB 8
#define CC 256
#define NN 1024     // H*W
#define HEADS 8
#define HDIM 32
#define NGRP 8

using bf16x8 = __attribute__((ext_vector_type(8))) short;
using f32x4  = __attribute__((ext_vector_type(4))) float;

static __device__ __forceinline__ ushort f2bf(float x) {
  unsigned u = __float_as_uint(x);
  unsigned r = (u + 0x7FFFu + ((u >> 16) & 1u)) >> 16;  // RNE
  return (ushort)r;
}

// ---------------------------------------------------------------------------
// Kernel 1: GroupNorm (unchanged from R1 — 2.6 µs-class, memory-bound).
// ---------------------------------------------------------------------------
__global__ __launch_bounds__(1024) void gn_kernel(
    const float* __restrict__ x, const float* __restrict__ gns,
    const float* __restrict__ gnb, float* __restrict__ h)
{
  const int t = threadIdx.x;
  const int b = blockIdx.x >> 3, g = blockIdx.x & 7;
  const size_t base4 = (((size_t)b * CC + (size_t)g * 32) * NN) >> 2;
  const float4* x4 = (const float4*)x + base4;
  float4* h4 = (float4*)h + base4;

  float4 r[8];
  float s = 0.f, ss = 0.f;
#pragma unroll
  for (int j = 0; j < 8; ++j) {
    r[j] = x4[t + j * 1024];
    s  += r[j].x + r[j].y + r[j].z + r[j].w;
    ss += r[j].x * r[j].x + r[j].y * r[j].y + r[j].z * r[j].z + r[j].w * r[j].w;
  }
#pragma unroll
  for (int off = 32; off > 0; off >>= 1) {
    s  += __shfl_down(s, off);
    ss += __shfl_down(ss, off);
  }
  __shared__ float rs[16], rss[16];
  __shared__ float smean, srstd;
  const int wid = t >> 6, lane = t & 63;
  if (lane == 0) { rs[wid] = s; rss[wid] = ss; }
  __syncthreads();
  if (t == 0) {
    float S = 0.f, SS = 0.f;
    for (int i = 0; i < 16; ++i) { S += rs[i]; SS += rss[i]; }
    const float mean = S * (1.f / 32768.f);
    const float var = SS * (1.f / 32768.f) - mean * mean;
    smean = mean;
    srstd = rsqrtf(var + 1e-5f);
  }
  __syncthreads();
  const float mean = smean, rstd = srstd;
#pragma unroll
  for (int j = 0; j < 8; ++j) {
    const int c = g * 32 + (t >> 8) + 4 * j;
    const float sc = gns[c] * rstd;
    const float bi = gnb[c];
    float4 o;
    o.x = (r[j].x - mean) * sc + bi;
    o.y = (r[j].y - mean) * sc + bi;
    o.z = (r[j].z - mean) * sc + bi;
    o.w = (r[j].w - mean) * sc + bi;
    h4[t + j * 1024] = o;
  }
}

// ---------------------------------------------------------------------------
// Kernel 2: QKV conv (fp32 GEMM core, R1-proven) with bf16 MFMA-layout
// epilogue:  Q -> qT[bh][n][32d] (scale 1/sqrt(32) folded)
//            K -> kT[bh][m][32d]
//            V -> vN[bh][32d][n] (natural)
// ---------------------------------------------------------------------------
__global__ __launch_bounds__(256) void conv_qkv_kernel(
    const float* __restrict__ W, const float* __restrict__ bias,
    const float* __restrict__ X,
    ushort* __restrict__ qT, ushort* __restrict__ kT, ushort* __restrict__ vN)
{
  const int t = threadIdx.x;
  const int tx = t & 15, ty = t >> 4;
  const int b = blockIdx.z;
  const int o0 = blockIdx.y << 6, n0 = blockIdx.x << 6;
  __shared__ float As[32][68];  // [k][o]
  __shared__ float Bs[32][68];  // [k][n]
  float acc[4][4] = {};
  const float* Xb = X + (size_t)b * CC * NN;

  for (int k0 = 0; k0 < 256; k0 += 32) {
#pragma unroll
    for (int l = 0; l < 2; ++l) {
      const int fi = t + (l << 8);  // 0..511
      const int o = fi >> 3, kq = fi & 7;
      const float4 w4 = *(const float4*)(W + (size_t)(o0 + o) * 256 + k0 + kq * 4);
      As[kq * 4 + 0][o] = w4.x;
      As[kq * 4 + 1][o] = w4.y;
      As[kq * 4 + 2][o] = w4.z;
      As[kq * 4 + 3][o] = w4.w;
      const int k = fi >> 4, nq = fi & 15;
      *(float4*)(&Bs[k][nq * 4]) =
          *(const float4*)(Xb + (size_t)(k0 + k) * NN + n0 + nq * 4);
    }
    __syncthreads();
#pragma unroll
    for (int k = 0; k < 32; ++k) {
      const float4 a  = *(const float4*)(&As[k][ty * 4]);
      const float4 bv = *(const float4*)(&Bs[k][tx * 4]);
      acc[0][0] += a.x * bv.x; acc[0][1] += a.x * bv.y; acc[0][2] += a.x * bv.z; acc[0][3] += a.x * bv.w;
      acc[1][0] += a.y * bv.x; acc[1][1] += a.y * bv.y; acc[1][2] += a.y * bv.z; acc[1][3] += a.y * bv.w;
      acc[2][0] += a.z * bv.x; acc[2][1] += a.z * bv.y; acc[2][2] += a.z * bv.z; acc[2][3] += a.z * bv.w;
      acc[3][0] += a.w * bv.x; acc[3][1] += a.w * bv.y; acc[3][2] += a.w * bv.z; acc[3][3] += a.w * bv.w;
    }
    __syncthreads();
  }

  const int osec = blockIdx.y >> 2;          // 0=Q, 1=K, 2=V
  const int oin  = (blockIdx.y & 3) << 6;    // offset within 256-ch section
  if (osec == 2) {
    // V natural: vN[((b*8+h)*32 + d)*1024 + n], vector along n
#pragma unroll
    for (int i = 0; i < 4; ++i) {
      const int oo = oin + ty * 4 + i;
      const int hh = oo >> 5, d = oo & 31;
      const float bi = bias[o0 + ty * 4 + i];
      ushort4 w;
      w.x = f2bf(acc[i][0] + bi); w.y = f2bf(acc[i][1] + bi);
      w.z = f2bf(acc[i][2] + bi); w.w = f2bf(acc[i][3] + bi);
      *(ushort4*)&vN[(((size_t)b * 8 + hh) * 32 + d) * 1024 + n0 + tx * 4] = w;
    }
  } else {
    // Q/K transposed: dst[((b*8+h)*1024 + n)*32 + d], vector along d (o)
    ushort* dst = osec ? kT : qT;
    const float scl = osec ? 1.0f : 0.17677669529663689f;  // 1/sqrt(32) on Q
    const int oo = oin + ty * 4;
    const int hh = oo >> 5, d0 = oo & 31;
    float bi[4];
#pragma unroll
    for (int i = 0; i < 4; ++i) bi[i] = bias[o0 + ty * 4 + i];
#pragma unroll
    for (int j = 0; j < 4; ++j) {
      const int n = n0 + tx * 4 + j;
      ushort4 w;
      w.x = f2bf((acc[0][j] + bi[0]) * scl);
      w.y = f2bf((acc[1][j] + bi[1]) * scl);
      w.z = f2bf((acc[2][j] + bi[2]) * scl);
      w.w = f2bf((acc[3][j] + bi[3]) * scl);
      *(ushort4*)&dst[(((size_t)b * 8 + hh) * 1024 + n) * 32 + d0] = w;
    }
  }
}

// ---------------------------------------------------------------------------
// Kernel 3: bf16 MFMA flash attention.
// Block = 256 threads (4 waves). Wave w owns 16 q-rows. Grid (16, 64).
// Swapped QK^T: S^T = mfma(A=K_frag, B=Q_frag) -> lane's P values share
// n = lane&15 -> softmax reduce = shfl_xor(16,32); P feeds PV's B operand
// in-register. PV: O^T = mfma(A=V_frag, B=P_frag).
// Fragment maps (16x16x32): A[row=l&15][k=(l>>4)*4+(j&3)+16*(j>>2)],
// B[k=same][col=l&15], D[row=(l>>4)*4+reg][col=l&15].
// ---------------------------------------------------------------------------
__global__ __launch_bounds__(256) void attn_kernel(
    const ushort* __restrict__ qT, const ushort* __restrict__ kT,
    const ushort* __restrict__ vN, float* __restrict__ ao)
{
  const int t = threadIdx.x;
  const int w = t >> 6, l = t & 63;
  const int lg = l >> 4, lr = l & 15;   // lane group / lane row
  const int bh = blockIdx.y;
  const int qbase = blockIdx.x << 6;

  __shared__ ushort Ks[64][40];  // [m][d], row 80 B (16B-aligned, 2-way max)
  __shared__ ushort Vs[32][72];  // [d][m], row 144 B (16B-aligned, 2-way max)

  union FragU { ushort4 u[2]; bf16x8 f; };

  // Q fragment: one per wave, lives in 4 VGPRs. B[k=d][col=n].
  FragU qf;
  {
    const ushort* Qp = qT + (((size_t)bh * 1024 + qbase + w * 16 + lr) * 32) + lg * 4;
    qf.u[0] = *(const ushort4*)Qp;
    qf.u[1] = *(const ushort4*)(Qp + 16);
  }

  f32x4 accO[2] = {};          // O^T: d-tile 0 (d=row) and 1 (d=row+16), col=n
  float m_st = -1e30f, l_st = 0.f;

  const ushort* Kbh = kT + (size_t)bh * 1024 * 32;
  const ushort* Vbh = vN + (size_t)bh * 32 * 1024;

  for (int m0 = 0; m0 < NN; m0 += 64) {
    __syncthreads();
    // Stage K^T tile: 64 m x 32 d, contiguous 4 KB in global.
    {
      const uint4 kv = ((const uint4*)(Kbh + (size_t)m0 * 32))[t];
      *(uint4*)&Ks[t >> 2][(t & 3) * 8] = kv;
      // Stage V tile: 32 d rows x 64 m.
      const int d = t >> 3, mq = t & 7;
      const uint4 vv = *(const uint4*)(Vbh + (size_t)d * 1024 + m0 + mq * 8);
      *(uint4*)&Vs[d][mq * 8] = vv;
    }
    __syncthreads();

    // S^T = K · Q^T : 4 MFMAs (m-subtiles of 16), K-dim = d = 32.
    f32x4 s[4];
#pragma unroll
    for (int ms = 0; ms < 4; ++ms) {
      FragU kf;
      const ushort* kp = &Ks[ms * 16 + lr][lg * 4];
      kf.u[0] = *(const ushort4*)kp;
      kf.u[1] = *(const ushort4*)(kp + 16);
      f32x4 z = {0.f, 0.f, 0.f, 0.f};
      s[ms] = __builtin_amdgcn_mfma_f32_16x16x32_bf16(kf.f, qf.f, z, 0, 0, 0);
    }

    // Online softmax. All of this lane's 16 S values share column n = lr.
    float mx = s[0][0];
#pragma unroll
    for (int ms = 0; ms < 4; ++ms)
#pragma unroll
      for (int r = 0; r < 4; ++r) mx = fmaxf(mx, s[ms][r]);
    mx = fmaxf(mx, __shfl_xor(mx, 16));
    mx = fmaxf(mx, __shfl_xor(mx, 32));
    const float mnew = fmaxf(m_st, mx);
    const float c = __expf(m_st - mnew);
    m_st = mnew;
    float ls = 0.f;
#pragma unroll
    for (int ms = 0; ms < 4; ++ms)
#pragma unroll
      for (int r = 0; r < 4; ++r) {
        const float p = __expf(s[ms][r] - mnew);
        s[ms][r] = p;
        ls += p;
      }
    ls += __shfl_xor(ls, 16);
    ls += __shfl_xor(ls, 32);
    l_st = l_st * c + ls;
#pragma unroll
    for (int dt = 0; dt < 2; ++dt)
#pragma unroll
      for (int r = 0; r < 4; ++r) accO[dt][r] *= c;

    // P -> bf16 B-fragments. mchunk mc covers m in [32mc, 32mc+32):
    // elems 0-3 <- s[2mc] regs, elems 4-7 <- s[2mc+1] regs.
    bf16x8 pb[2];
#pragma unroll
    for (int mc = 0; mc < 2; ++mc) {
      bf16x8 f;
#pragma unroll
      for (int r = 0; r < 4; ++r) {
        f[r]     = (short)f2bf(s[2 * mc][r]);
        f[r + 4] = (short)f2bf(s[2 * mc + 1][r]);
      }
      pb[mc] = f;
    }

    // PV: O^T[d][n] += V[d][m] * P^T[m][n]. A = V frag, B = pb.
#pragma unroll
    for (int dt = 0; dt < 2; ++dt) {
#pragma unroll
      for (int mc = 0; mc < 2; ++mc) {
        FragU vf;
        const ushort* vp = &Vs[dt * 16 + lr][mc * 32 + lg * 4];
        vf.u[0] = *(const ushort4*)vp;
        vf.u[1] = *(const ushort4*)(vp + 16);
        accO[dt] = __builtin_amdgcn_mfma_f32_16x16x32_bf16(vf.f, pb[mc], accO[dt], 0, 0, 0);
      }
    }
  }

  // Epilogue: divide by l and write fp32 ao[b][c][n] (c = h*32 + d).
  const float inv = 1.f / l_st;
  const int n = qbase + w * 16 + lr;
#pragma unroll
  for (int dt = 0; dt < 2; ++dt)
#pragma unroll
    for (int r = 0; r < 4; ++r) {
      const int d = dt * 16 + lg * 4 + r;
      ao[((size_t)bh * 32 + d) * 1024 + n] = accO[dt][r] * inv;
    }
}

// ---------------------------------------------------------------------------
// Kernel 4: out-proj conv, fp32 (unchanged), with residual.
// ---------------------------------------------------------------------------
__global__ __launch_bounds__(256) void conv1x1_kernel(
    const float* __restrict__ W, const float* __restrict__ bias,
    const float* __restrict__ X, const float* __restrict__ R,
    float* __restrict__ Y, int O)
{
  const int t = threadIdx.x;
  const int tx = t & 15, ty = t >> 4;
  const int b = blockIdx.z;
  const int o0 = blockIdx.y << 6, n0 = blockIdx.x << 6;
  __shared__ float As[32][68];
  __shared__ float Bs[32][68];
  float acc[4][4] = {};
  const float* Xb = X + (size_t)b * CC * NN;

  for (int k0 = 0; k0 < 256; k0 += 32) {
#pragma unroll
    for (int l = 0; l < 2; ++l) {
      const int fi = t + (l << 8);
      const int o = fi >> 3, kq = fi & 7;
      const float4 w4 = *(const float4*)(W + (size_t)(o0 + o) * 256 + k0 + kq * 4);
      As[kq * 4 + 0][o] = w4.x;
      As[kq * 4 + 1][o] = w4.y;
      As[kq * 4 + 2][o] = w4.z;
      As[kq * 4 + 3][o] = w4.w;
      const int k = fi >> 4, nq = fi & 15;
      *(float4*)(&Bs[k][nq * 4]) =
          *(const float4*)(Xb + (size_t)(k0 + k) * NN + n0 + nq * 4);
    }
    __syncthreads();
#pragma unroll
    for (int k = 0; k < 32; ++k) {
      const float4 a  = *(const float4*)(&As[k][ty * 4]);
      const float4 bv = *(const float4*)(&Bs[k][tx * 4]);
      acc[0][0] += a.x * bv.x; acc[0][1] += a.x * bv.y; acc[0][2] += a.x * bv.z; acc[0][3] += a.x * bv.w;
      acc[1][0] += a.y * bv.x; acc[1][1] += a.y * bv.y; acc[1][2] += a.y * bv.z; acc[1][3] += a.y * bv.w;
      acc[2][0] += a.z * bv.x; acc[2][1] += a.z * bv.y; acc[2][2] += a.z * bv.z; acc[2][3] += a.z * bv.w;
      acc[3][0] += a.w * bv.x; acc[3][1] += a.w * bv.y; acc[3][2] += a.w * bv.z; acc[3][3] += a.w * bv.w;
    }
    __syncthreads();
  }
#pragma unroll
  for (int i = 0; i < 4; ++i) {
    const int o = o0 + ty * 4 + i;
    const float bi = bias[o];
    float4 v;
    v.x = acc[i][0] + bi; v.y = acc[i][1] + bi;
    v.z = acc[i][2] + bi; v.w = acc[i][3] + bi;
    const size_t idx = ((size_t)b * O + o) * NN + n0 + tx * 4;
    if (R) {
      const float4 r4 = *(const float4*)(R + idx);
      v.x += r4.x; v.y += r4.y; v.z += r4.z; v.w += r4.w;
    }
    *(float4*)(Y + idx) = v;
  }
}

// ---------------------------------------------------------------------------
// Launch. ws layout (bytes):
//   h   fp32  @ 0        (8 MB)
//   qT  bf16  @ 8  MB    (4 MB)   [bh][n][32d], pre-scaled
//   kT  bf16  @ 12 MB    (4 MB)   [bh][m][32d]
//   vN  bf16  @ 16 MB    (4 MB)   [bh][32d][n]
//   ao  fp32  @ 20 MB    (8 MB)   [b][c][n]
// ---------------------------------------------------------------------------
extern "C" void kernel_launch(void* const* d_in, const int* in_sizes, int n_in,
                              void* d_out, int out_size, void* d_ws, size_t ws_size,
                              hipStream_t stream)
{
  const float* x    = (const float*)d_in[0];
  const float* gns  = (const float*)d_in[1];
  const float* gnb  = (const float*)d_in[2];
  const float* wqkv = (const float*)d_in[3];
  const float* bqkv = (const float*)d_in[4];
  const float* wout = (const float*)d_in[5];
  const float* bout = (const float*)d_in[6];
  float* out = (float*)d_out;

  char* ws = (char*)d_ws;
  float*  h  = (float*)(ws);
  ushort* qT = (ushort*)(ws + (8u << 20));
  ushort* kT = (ushort*)(ws + (12u << 20));
  ushort* vN = (ushort*)(ws + (16u << 20));
  float*  ao = (float*)(ws + (20u << 20));

  gn_kernel<<<dim3(64), dim3(1024), 0, stream>>>(x, gns, gnb, h);
  conv_qkv_kernel<<<dim3(16, 12, 8), dim3(256), 0, stream>>>(wqkv, bqkv, h, qT, kT, vN);
  attn_kernel<<<dim3(16, 64), dim3(256), 0, stream>>>(qT, kT, vN, ao);
  conv1x1_kernel<<<dim3(16, 4, 8), dim3(256), 0, stream>>>(wout, bout, ao, x, out, 256);
}

// Round 3
// 138.250 us; speedup vs baseline: 4.0803x; 1.3352x over previous
//
#include <hip/hip_runtime.h>
#include <math.h>

// Problem constants
#define BB 8
#define CC 256
#define NN 1024     // H*W
#define HEADS 8
#define HDIM 32
#define NGRP 8

using bf16x8 = __attribute__((ext_vector_type(8))) short;
using f32x4  = __attribute__((ext_vector_type(4))) float;

static __device__ __forceinline__ ushort f2bf(float x) {
  unsigned u = __float_as_uint(x);
  unsigned r = (u + 0x7FFFu + ((u >> 16) & 1u)) >> 16;  // RNE
  return (ushort)r;
}

// ---------------------------------------------------------------------------
// Kernel 0: weights fp32 -> bf16 cast. wbf rows 0..767 = w_qkv, 768..1023 =
// w_out. Runs every launch (no static state allowed).
// ---------------------------------------------------------------------------
__global__ __launch_bounds__(256) void wcast_kernel(
    const float* __restrict__ wqkv, const float* __restrict__ wout,
    ushort* __restrict__ wbf)
{
  const int gid = blockIdx.x * 256 + threadIdx.x;  // 32768 threads
  const int e8 = gid * 8;
  const float* src = (e8 < 196608) ? (wqkv + e8) : (wout + (e8 - 196608));
  const float4 a = *(const float4*)src;
  const float4 c = *(const float4*)(src + 4);
  union { uint4 v; ushort s[8]; } o;
  o.s[0] = f2bf(a.x); o.s[1] = f2bf(a.y); o.s[2] = f2bf(a.z); o.s[3] = f2bf(a.w);
  o.s[4] = f2bf(c.x); o.s[5] = f2bf(c.y); o.s[6] = f2bf(c.z); o.s[7] = f2bf(c.w);
  *(uint4*)(wbf + e8) = o.v;
}

// ---------------------------------------------------------------------------
// Kernel 1: GroupNorm, now emitting bf16 h[b][c][n] (halves write traffic).
// ---------------------------------------------------------------------------
__global__ __launch_bounds__(1024) void gn_kernel(
    const float* __restrict__ x, const float* __restrict__ gns,
    const float* __restrict__ gnb, ushort* __restrict__ h)
{
  const int t = threadIdx.x;
  const int b = blockIdx.x >> 3, g = blockIdx.x & 7;
  const size_t base = (((size_t)b * CC + (size_t)g * 32) * NN);
  const float4* x4 = (const float4*)(x + base);
  ushort* hb = h + base;

  float4 r[8];
  float s = 0.f, ss = 0.f;
#pragma unroll
  for (int j = 0; j < 8; ++j) {
    r[j] = x4[t + j * 1024];
    s  += r[j].x + r[j].y + r[j].z + r[j].w;
    ss += r[j].x * r[j].x + r[j].y * r[j].y + r[j].z * r[j].z + r[j].w * r[j].w;
  }
#pragma unroll
  for (int off = 32; off > 0; off >>= 1) {
    s  += __shfl_down(s, off);
    ss += __shfl_down(ss, off);
  }
  __shared__ float rs[16], rss[16];
  __shared__ float smean, srstd;
  const int wid = t >> 6, lane = t & 63;
  if (lane == 0) { rs[wid] = s; rss[wid] = ss; }
  __syncthreads();
  if (t == 0) {
    float S = 0.f, SS = 0.f;
    for (int i = 0; i < 16; ++i) { S += rs[i]; SS += rss[i]; }
    const float mean = S * (1.f / 32768.f);
    const float var = SS * (1.f / 32768.f) - mean * mean;
    smean = mean;
    srstd = rsqrtf(var + 1e-5f);
  }
  __syncthreads();
  const float mean = smean, rstd = srstd;
#pragma unroll
  for (int j = 0; j < 8; ++j) {
    const int c = g * 32 + (t >> 8) + 4 * j;
    const float sc = gns[c] * rstd;
    const float bi = gnb[c];
    ushort4 w4;
    w4.x = f2bf((r[j].x - mean) * sc + bi);
    w4.y = f2bf((r[j].y - mean) * sc + bi);
    w4.z = f2bf((r[j].z - mean) * sc + bi);
    w4.w = f2bf((r[j].w - mean) * sc + bi);
    *(ushort4*)&hb[(size_t)(t + j * 1024) * 4] = w4;
  }
}

// ---------------------------------------------------------------------------
// Kernels 2 & 4: bf16 MFMA GEMM for the 1x1 convs.
//   Y[b][o][n] = sum_k W[o][k] X[b][k][n] (+bias, epilogue per MODE)
// Tile 64(o) x 64(n), BK=64, 4 waves in 2x2, each wave 32x32 (2x2 frags of
// 16x16x32). LDS rows padded to 72 ushorts (144B: 2-way on 8B frag reads =
// free). MODE 0 (qkv): X = h[c][n], transpose during staging (8 scalar LDS
// writes/thread, ~8-way on a 2B write — bounded); epilogue writes qT/kT/vN
// in attention-native layouts, Q-scale folded. MODE 1 (out): X = aoT[n][k]
// already transposed by attn epilogue -> uint4 direct staging; epilogue adds
// bias + residual x, writes fp32 out.
// ---------------------------------------------------------------------------
template <int MODE>
__global__ __launch_bounds__(256) void conv_mfma_kernel(
    const ushort* __restrict__ Wbf, const float* __restrict__ bias,
    const ushort* __restrict__ X, const float* __restrict__ xres,
    ushort* __restrict__ qT, ushort* __restrict__ kT, ushort* __restrict__ vN,
    float* __restrict__ out)
{
  const int t = threadIdx.x;
  const int w = t >> 6, l = t & 63;
  const int lg = l >> 4, lr = l & 15;
  const int wr = w >> 1, wc = w & 1;
  const int b = blockIdx.z;
  const int o0 = blockIdx.y << 6, n0 = blockIdx.x << 6;

  __shared__ ushort Ws[64][72];  // [o][k]
  __shared__ ushort Xs[64][72];  // [n][k]

  union FragU { ushort4 u[2]; bf16x8 f; };
  f32x4 acc[2][2] = {};  // [ms(o)][ns(n)]

  const ushort* Xb = X + (size_t)b * 256 * 1024;

  for (int k0 = 0; k0 < 256; k0 += 64) {
    __syncthreads();
#pragma unroll
    for (int li = 0; li < 2; ++li) {
      const int id = t + (li << 8);       // 0..511
      const int rr = id >> 3, c8 = id & 7;
      const uint4 wv = *(const uint4*)(Wbf + (size_t)(o0 + rr) * 256 + k0 + c8 * 8);
      *(uint4*)&Ws[rr][c8 * 8] = wv;
      if (MODE == 1) {
        const uint4 xv = *(const uint4*)(Xb + (size_t)(n0 + rr) * 256 + k0 + c8 * 8);
        *(uint4*)&Xs[rr][c8 * 8] = xv;
      } else {
        union { uint4 v; ushort s[8]; } xv;
        xv.v = *(const uint4*)(Xb + (size_t)(k0 + rr) * 1024 + n0 + c8 * 8);
#pragma unroll
        for (int j = 0; j < 8; ++j) Xs[c8 * 8 + j][rr] = xv.s[j];
      }
    }
    __syncthreads();

    FragU af[2][2], xf[2][2];  // [ms|ns][kc]
#pragma unroll
    for (int i = 0; i < 2; ++i)
#pragma unroll
      for (int kc = 0; kc < 2; ++kc) {
        const ushort* p = &Ws[wr * 32 + i * 16 + lr][kc * 32 + lg * 4];
        af[i][kc].u[0] = *(const ushort4*)p;
        af[i][kc].u[1] = *(const ushort4*)(p + 16);
        const ushort* q = &Xs[wc * 32 + i * 16 + lr][kc * 32 + lg * 4];
        xf[i][kc].u[0] = *(const ushort4*)q;
        xf[i][kc].u[1] = *(const ushort4*)(q + 16);
      }
#pragma unroll
    for (int ms = 0; ms < 2; ++ms)
#pragma unroll
      for (int ns = 0; ns < 2; ++ns) {
        acc[ms][ns] = __builtin_amdgcn_mfma_f32_16x16x32_bf16(af[ms][0].f, xf[ns][0].f, acc[ms][ns], 0, 0, 0);
        acc[ms][ns] = __builtin_amdgcn_mfma_f32_16x16x32_bf16(af[ms][1].f, xf[ns][1].f, acc[ms][ns], 0, 0, 0);
      }
  }

  // Epilogue. D frag: row(o) = lg*4 + reg, col(n) = lr (within 16x16).
  if (MODE == 0) {
    const int sec = o0 >> 8;  // 0=Q, 1=K, 2=V (o-tile never crosses sections)
    const float scl = (sec == 0) ? 0.17677669529663689f : 1.0f;
#pragma unroll
    for (int ms = 0; ms < 2; ++ms) {
      const int ob = o0 + wr * 32 + ms * 16 + lg * 4;  // 4 consecutive o
      const float4 b4 = *(const float4*)(bias + ob);
      const int oo = ob & 255;
      const int hh = oo >> 5, d0 = oo & 31;
      const int bh = b * 8 + hh;
#pragma unroll
      for (int ns = 0; ns < 2; ++ns) {
        const int n = n0 + wc * 32 + ns * 16 + lr;
        float v0 = (acc[ms][ns][0] + b4.x) * scl;
        float v1 = (acc[ms][ns][1] + b4.y) * scl;
        float v2 = (acc[ms][ns][2] + b4.z) * scl;
        float v3 = (acc[ms][ns][3] + b4.w) * scl;
        if (sec < 2) {
          ushort* dst = (sec == 0) ? qT : kT;
          ushort4 w4 = {f2bf(v0), f2bf(v1), f2bf(v2), f2bf(v3)};
          *(ushort4*)&dst[((size_t)bh * 1024 + n) * 32 + d0] = w4;
        } else {
          vN[((size_t)bh * 32 + d0 + 0) * 1024 + n] = f2bf(v0);
          vN[((size_t)bh * 32 + d0 + 1) * 1024 + n] = f2bf(v1);
          vN[((size_t)bh * 32 + d0 + 2) * 1024 + n] = f2bf(v2);
          vN[((size_t)bh * 32 + d0 + 3) * 1024 + n] = f2bf(v3);
        }
      }
    }
  } else {
#pragma unroll
    for (int ms = 0; ms < 2; ++ms) {
      const int ob = o0 + wr * 32 + ms * 16 + lg * 4;
      const float4 b4 = *(const float4*)(bias + ob);
#pragma unroll
      for (int ns = 0; ns < 2; ++ns) {
        const int n = n0 + wc * 32 + ns * 16 + lr;
        const size_t i0 = ((size_t)b * 256 + ob) * 1024 + n;
        out[i0]          = acc[ms][ns][0] + b4.x + xres[i0];
        out[i0 + 1024]   = acc[ms][ns][1] + b4.y + xres[i0 + 1024];
        out[i0 + 2048]   = acc[ms][ns][2] + b4.z + xres[i0 + 2048];
        out[i0 + 3072]   = acc[ms][ns][3] + b4.w + xres[i0 + 3072];
      }
    }
  }
}

// ---------------------------------------------------------------------------
// Kernel 3: bf16 MFMA flash attention (R2-verified core). Epilogue now emits
// aoT[b][n][c] bf16 (transposed + 2 vector stores) so the out-proj GEMM
// stages it directly.
// ---------------------------------------------------------------------------
__global__ __launch_bounds__(256) void attn_kernel(
    const ushort* __restrict__ qT, const ushort* __restrict__ kT,
    const ushort* __restrict__ vN, ushort* __restrict__ aoT)
{
  const int t = threadIdx.x;
  const int w = t >> 6, l = t & 63;
  const int lg = l >> 4, lr = l & 15;
  const int bh = blockIdx.y;
  const int b = bh >> 3, hh = bh & 7;
  const int qbase = blockIdx.x << 6;

  __shared__ ushort Ks[64][40];  // [m][d]
  __shared__ ushort Vs[32][72];  // [d][m]

  union FragU { ushort4 u[2]; bf16x8 f; };

  FragU qf;
  {
    const ushort* Qp = qT + (((size_t)bh * 1024 + qbase + w * 16 + lr) * 32) + lg * 4;
    qf.u[0] = *(const ushort4*)Qp;
    qf.u[1] = *(const ushort4*)(Qp + 16);
  }

  f32x4 accO[2] = {};
  float m_st = -1e30f, l_st = 0.f;

  const ushort* Kbh = kT + (size_t)bh * 1024 * 32;
  const ushort* Vbh = vN + (size_t)bh * 32 * 1024;

  for (int m0 = 0; m0 < NN; m0 += 64) {
    __syncthreads();
    {
      const uint4 kv = ((const uint4*)(Kbh + (size_t)m0 * 32))[t];
      *(uint4*)&Ks[t >> 2][(t & 3) * 8] = kv;
      const int d = t >> 3, mq = t & 7;
      const uint4 vv = *(const uint4*)(Vbh + (size_t)d * 1024 + m0 + mq * 8);
      *(uint4*)&Vs[d][mq * 8] = vv;
    }
    __syncthreads();

    f32x4 s[4];
#pragma unroll
    for (int ms = 0; ms < 4; ++ms) {
      FragU kf;
      const ushort* kp = &Ks[ms * 16 + lr][lg * 4];
      kf.u[0] = *(const ushort4*)kp;
      kf.u[1] = *(const ushort4*)(kp + 16);
      f32x4 z = {0.f, 0.f, 0.f, 0.f};
      s[ms] = __builtin_amdgcn_mfma_f32_16x16x32_bf16(kf.f, qf.f, z, 0, 0, 0);
    }

    float mx = s[0][0];
#pragma unroll
    for (int ms = 0; ms < 4; ++ms)
#pragma unroll
      for (int r = 0; r < 4; ++r) mx = fmaxf(mx, s[ms][r]);
    mx = fmaxf(mx, __shfl_xor(mx, 16));
    mx = fmaxf(mx, __shfl_xor(mx, 32));
    const float mnew = fmaxf(m_st, mx);
    const float c = __expf(m_st - mnew);
    m_st = mnew;
    float ls = 0.f;
#pragma unroll
    for (int ms = 0; ms < 4; ++ms)
#pragma unroll
      for (int r = 0; r < 4; ++r) {
        const float p = __expf(s[ms][r] - mnew);
        s[ms][r] = p;
        ls += p;
      }
    ls += __shfl_xor(ls, 16);
    ls += __shfl_xor(ls, 32);
    l_st = l_st * c + ls;
#pragma unroll
    for (int dt = 0; dt < 2; ++dt)
#pragma unroll
      for (int r = 0; r < 4; ++r) accO[dt][r] *= c;

    bf16x8 pb[2];
#pragma unroll
    for (int mc = 0; mc < 2; ++mc) {
      bf16x8 f;
#pragma unroll
      for (int r = 0; r < 4; ++r) {
        f[r]     = (short)f2bf(s[2 * mc][r]);
        f[r + 4] = (short)f2bf(s[2 * mc + 1][r]);
      }
      pb[mc] = f;
    }

#pragma unroll
    for (int dt = 0; dt < 2; ++dt) {
#pragma unroll
      for (int mc = 0; mc < 2; ++mc) {
        FragU vf;
        const ushort* vp = &Vs[dt * 16 + lr][mc * 32 + lg * 4];
        vf.u[0] = *(const ushort4*)vp;
        vf.u[1] = *(const ushort4*)(vp + 16);
        accO[dt] = __builtin_amdgcn_mfma_f32_16x16x32_bf16(vf.f, pb[mc], accO[dt], 0, 0, 0);
      }
    }
  }

  const float inv = 1.f / l_st;
  const int n = qbase + w * 16 + lr;
  ushort* ap = aoT + ((size_t)b * 1024 + n) * 256 + hh * 32 + lg * 4;
#pragma unroll
  for (int dt = 0; dt < 2; ++dt) {
    ushort4 w4;
    w4.x = f2bf(accO[dt][0] * inv);
    w4.y = f2bf(accO[dt][1] * inv);
    w4.z = f2bf(accO[dt][2] * inv);
    w4.w = f2bf(accO[dt][3] * inv);
    *(ushort4*)(ap + dt * 16) = w4;
  }
}

// ---------------------------------------------------------------------------
// Launch. ws layout (bytes, all bf16 except noted):
//   h   [8][256][1024]  @ 0     (4 MB)
//   qT  [64][1024][32]  @ 4 MB  (4 MB)   pre-scaled 1/sqrt(32)
//   kT  [64][1024][32]  @ 8 MB  (4 MB)
//   vN  [64][32][1024]  @ 12 MB (4 MB)
//   aoT [8][1024][256]  @ 16 MB (4 MB)
//   wbf [1024][256]     @ 20 MB (0.5 MB; rows 768+ = w_out)
// ---------------------------------------------------------------------------
extern "C" void kernel_launch(void* const* d_in, const int* in_sizes, int n_in,
                              void* d_out, int out_size, void* d_ws, size_t ws_size,
                              hipStream_t stream)
{
  const float* x    = (const float*)d_in[0];
  const float* gns  = (const float*)d_in[1];
  const float* gnb  = (const float*)d_in[2];
  const float* wqkv = (const float*)d_in[3];
  const float* bqkv = (const float*)d_in[4];
  const float* wout = (const float*)d_in[5];
  const float* bout = (const float*)d_in[6];
  float* out = (float*)d_out;

  char* ws = (char*)d_ws;
  ushort* h   = (ushort*)(ws);
  ushort* qT  = (ushort*)(ws + (4u << 20));
  ushort* kT  = (ushort*)(ws + (8u << 20));
  ushort* vN  = (ushort*)(ws + (12u << 20));
  ushort* aoT = (ushort*)(ws + (16u << 20));
  ushort* wbf = (ushort*)(ws + (20u << 20));

  wcast_kernel<<<dim3(128), dim3(256), 0, stream>>>(wqkv, wout, wbf);
  gn_kernel<<<dim3(64), dim3(1024), 0, stream>>>(x, gns, gnb, h);
  conv_mfma_kernel<0><<<dim3(16, 12, 8), dim3(256), 0, stream>>>(
      wbf, bqkv, h, nullptr, qT, kT, vN, nullptr);
  attn_kernel<<<dim3(16, 64), dim3(256), 0, stream>>>(qT, kT, vN, aoT);
  conv_mfma_kernel<1><<<dim3(16, 4, 8), dim3(256), 0, stream>>>(
      wbf + 768 * 256, bout, aoT, x, nullptr, nullptr, nullptr, out);
}

// Round 4
// 127.749 us; speedup vs baseline: 4.4157x; 1.0822x over previous
//
#include <hip/hip_runtime.h>
#include <hip/hip_bf16.h>
#include <math.h>

// Problem constants
#define BB 8
#define CC 256
#define NN 1024     // H*W
#define HEADS 8
#define HDIM 32
#define NGRP 8

using bf16x8 = __attribute__((ext_vector_type(8))) short;
using f32x4  = __attribute__((ext_vector_type(4))) float;

#if __has_builtin(__builtin_amdgcn_exp2f)
#define EXP2(x) __builtin_amdgcn_exp2f(x)
#else
#define EXP2(x) exp2f(x)
#endif

// 1/sqrt(32) * log2(e): Q pre-scale so softmax exp becomes native v_exp_f32
#define SCL_Q_LOG2E 0.2550348892803828f

static __device__ __forceinline__ ushort f2bf(float x) {
  union { __hip_bfloat16 b; ushort u; } c;
  c.b = __float2bfloat16(x);   // RNE; compiler can pack pairs into v_cvt_pk_bf16_f32
  return c.u;
}

// ---------------------------------------------------------------------------
// Kernel 0: weights fp32 -> bf16 cast.
// ---------------------------------------------------------------------------
__global__ __launch_bounds__(256) void wcast_kernel(
    const float* __restrict__ wqkv, const float* __restrict__ wout,
    ushort* __restrict__ wbf)
{
  const int gid = blockIdx.x * 256 + threadIdx.x;  // 32768 threads
  const int e8 = gid * 8;
  const float* src = (e8 < 196608) ? (wqkv + e8) : (wout + (e8 - 196608));
  const float4 a = *(const float4*)src;
  const float4 c = *(const float4*)(src + 4);
  union { uint4 v; ushort s[8]; } o;
  o.s[0] = f2bf(a.x); o.s[1] = f2bf(a.y); o.s[2] = f2bf(a.z); o.s[3] = f2bf(a.w);
  o.s[4] = f2bf(c.x); o.s[5] = f2bf(c.y); o.s[6] = f2bf(c.z); o.s[7] = f2bf(c.w);
  *(uint4*)(wbf + e8) = o.v;
}

// ---------------------------------------------------------------------------
// Kernel 1: GroupNorm -> bf16 h[b][c][n] (R3-proven).
// ---------------------------------------------------------------------------
__global__ __launch_bounds__(1024) void gn_kernel(
    const float* __restrict__ x, const float* __restrict__ gns,
    const float* __restrict__ gnb, ushort* __restrict__ h)
{
  const int t = threadIdx.x;
  const int b = blockIdx.x >> 3, g = blockIdx.x & 7;
  const size_t base = (((size_t)b * CC + (size_t)g * 32) * NN);
  const float4* x4 = (const float4*)(x + base);
  ushort* hb = h + base;

  float4 r[8];
  float s = 0.f, ss = 0.f;
#pragma unroll
  for (int j = 0; j < 8; ++j) {
    r[j] = x4[t + j * 1024];
    s  += r[j].x + r[j].y + r[j].z + r[j].w;
    ss += r[j].x * r[j].x + r[j].y * r[j].y + r[j].z * r[j].z + r[j].w * r[j].w;
  }
#pragma unroll
  for (int off = 32; off > 0; off >>= 1) {
    s  += __shfl_down(s, off);
    ss += __shfl_down(ss, off);
  }
  __shared__ float rs[16], rss[16];
  __shared__ float smean, srstd;
  const int wid = t >> 6, lane = t & 63;
  if (lane == 0) { rs[wid] = s; rss[wid] = ss; }
  __syncthreads();
  if (t == 0) {
    float S = 0.f, SS = 0.f;
    for (int i = 0; i < 16; ++i) { S += rs[i]; SS += rss[i]; }
    const float mean = S * (1.f / 32768.f);
    const float var = SS * (1.f / 32768.f) - mean * mean;
    smean = mean;
    srstd = rsqrtf(var + 1e-5f);
  }
  __syncthreads();
  const float mean = smean, rstd = srstd;
#pragma unroll
  for (int j = 0; j < 8; ++j) {
    const int c = g * 32 + (t >> 8) + 4 * j;
    const float sc = gns[c] * rstd;
    const float bi = gnb[c];
    ushort4 w4;
    w4.x = f2bf((r[j].x - mean) * sc + bi);
    w4.y = f2bf((r[j].y - mean) * sc + bi);
    w4.z = f2bf((r[j].z - mean) * sc + bi);
    w4.w = f2bf((r[j].w - mean) * sc + bi);
    *(ushort4*)&hb[(size_t)(t + j * 1024) * 4] = w4;
  }
}

// ---------------------------------------------------------------------------
// Kernel 1b: transpose h[b][c][n] -> hT[b][n][c]. 64x64 ushort tiles via LDS
// (pitch 68: phase-1 scalar-write / phase-2 ushort4-read both ~4-way max,
// hidden under DRAM). Grid (16 n-tiles, 4 c-tiles, 8 b) x 256 thr.
// ---------------------------------------------------------------------------
__global__ __launch_bounds__(256) void transpose_kernel(
    const ushort* __restrict__ h, ushort* __restrict__ hT)
{
  __shared__ ushort Ls[64 * 68];  // [n][c] pitch 68
  const int t = threadIdx.x;
  const int b = blockIdx.z;
  const int c0 = blockIdx.y << 6, n0 = blockIdx.x << 6;
  const ushort* hb = h + ((size_t)b * CC) * NN;

#pragma unroll
  for (int li = 0; li < 2; ++li) {
    const int id = t + (li << 8);       // 0..511
    const int cR = id >> 3, nC = id & 7;
    union { uint4 v; ushort s[8]; } xv;
    xv.v = *(const uint4*)(hb + (size_t)(c0 + cR) * NN + n0 + nC * 8);
#pragma unroll
    for (int j = 0; j < 8; ++j) Ls[(nC * 8 + j) * 68 + cR] = xv.s[j];
  }
  __syncthreads();
#pragma unroll
  for (int li = 0; li < 2; ++li) {
    const int id = t + (li << 8);
    const int nR = id >> 3, cP = id & 7;
    union { uint4 v; ushort4 s[2]; } ov;
    ov.s[0] = *(const ushort4*)&Ls[nR * 68 + cP * 8];
    ov.s[1] = *(const ushort4*)&Ls[nR * 68 + cP * 8 + 4];
    *(uint4*)(hT + ((size_t)b * NN + n0 + nR) * CC + c0 + cP * 8) = ov.v;
  }
}

// ---------------------------------------------------------------------------
// Kernels 2 & 4: bf16 MFMA GEMM for the 1x1 convs. X is ALWAYS [row=n][k]
// (hT for MODE 0, aoT for MODE 1) -> identical conflict-free uint4 staging.
// Tile 64(o) x 64(n), BK=64, 4 waves 2x2, wave 32x32 = 2x2 frags 16x16x32.
// MODE gates the epilogue only.
// ---------------------------------------------------------------------------
template <int MODE>
__global__ __launch_bounds__(256) void conv_mfma_kernel(
    const ushort* __restrict__ Wbf, const float* __restrict__ bias,
    const ushort* __restrict__ X, const float* __restrict__ xres,
    ushort* __restrict__ qT, ushort* __restrict__ kT, ushort* __restrict__ vN,
    float* __restrict__ out)
{
  const int t = threadIdx.x;
  const int w = t >> 6, l = t & 63;
  const int lg = l >> 4, lr = l & 15;
  const int wr = w >> 1, wc = w & 1;
  const int b = blockIdx.z;
  const int o0 = blockIdx.y << 6, n0 = blockIdx.x << 6;

  __shared__ ushort Ws[64][72];  // [o][k]
  __shared__ ushort Xs[64][72];  // [n][k]

  union FragU { ushort4 u[2]; bf16x8 f; };
  f32x4 acc[2][2] = {};  // [ms(o)][ns(n)]

  const ushort* Xb = X + (size_t)b * 1024 * 256;

  for (int k0 = 0; k0 < 256; k0 += 64) {
    __syncthreads();
#pragma unroll
    for (int li = 0; li < 2; ++li) {
      const int id = t + (li << 8);       // 0..511
      const int rr = id >> 3, c8 = id & 7;
      const uint4 wv = *(const uint4*)(Wbf + (size_t)(o0 + rr) * 256 + k0 + c8 * 8);
      *(uint4*)&Ws[rr][c8 * 8] = wv;
      const uint4 xv = *(const uint4*)(Xb + (size_t)(n0 + rr) * 256 + k0 + c8 * 8);
      *(uint4*)&Xs[rr][c8 * 8] = xv;
    }
    __syncthreads();

    FragU af[2][2], xf[2][2];  // [ms|ns][kc]
#pragma unroll
    for (int i = 0; i < 2; ++i)
#pragma unroll
      for (int kc = 0; kc < 2; ++kc) {
        const ushort* p = &Ws[wr * 32 + i * 16 + lr][kc * 32 + lg * 4];
        af[i][kc].u[0] = *(const ushort4*)p;
        af[i][kc].u[1] = *(const ushort4*)(p + 16);
        const ushort* q = &Xs[wc * 32 + i * 16 + lr][kc * 32 + lg * 4];
        xf[i][kc].u[0] = *(const ushort4*)q;
        xf[i][kc].u[1] = *(const ushort4*)(q + 16);
      }
#pragma unroll
    for (int ms = 0; ms < 2; ++ms)
#pragma unroll
      for (int ns = 0; ns < 2; ++ns) {
        acc[ms][ns] = __builtin_amdgcn_mfma_f32_16x16x32_bf16(af[ms][0].f, xf[ns][0].f, acc[ms][ns], 0, 0, 0);
        acc[ms][ns] = __builtin_amdgcn_mfma_f32_16x16x32_bf16(af[ms][1].f, xf[ns][1].f, acc[ms][ns], 0, 0, 0);
      }
  }

  // Epilogue. D frag: row(o) = lg*4 + reg, col(n) = lr (within 16x16).
  if (MODE == 0) {
    const int sec = o0 >> 8;  // 0=Q, 1=K, 2=V
    const float scl = (sec == 0) ? SCL_Q_LOG2E : 1.0f;
#pragma unroll
    for (int ms = 0; ms < 2; ++ms) {
      const int ob = o0 + wr * 32 + ms * 16 + lg * 4;  // 4 consecutive o
      const float4 b4 = *(const float4*)(bias + ob);
      const int oo = ob & 255;
      const int hh = oo >> 5, d0 = oo & 31;
      const int bh = b * 8 + hh;
#pragma unroll
      for (int ns = 0; ns < 2; ++ns) {
        const int n = n0 + wc * 32 + ns * 16 + lr;
        float v0 = (acc[ms][ns][0] + b4.x) * scl;
        float v1 = (acc[ms][ns][1] + b4.y) * scl;
        float v2 = (acc[ms][ns][2] + b4.z) * scl;
        float v3 = (acc[ms][ns][3] + b4.w) * scl;
        if (sec < 2) {
          ushort* dst = (sec == 0) ? qT : kT;
          ushort4 w4 = {f2bf(v0), f2bf(v1), f2bf(v2), f2bf(v3)};
          *(ushort4*)&dst[((size_t)bh * 1024 + n) * 32 + d0] = w4;
        } else {
          vN[((size_t)bh * 32 + d0 + 0) * 1024 + n] = f2bf(v0);
          vN[((size_t)bh * 32 + d0 + 1) * 1024 + n] = f2bf(v1);
          vN[((size_t)bh * 32 + d0 + 2) * 1024 + n] = f2bf(v2);
          vN[((size_t)bh * 32 + d0 + 3) * 1024 + n] = f2bf(v3);
        }
      }
    }
  } else {
#pragma unroll
    for (int ms = 0; ms < 2; ++ms) {
      const int ob = o0 + wr * 32 + ms * 16 + lg * 4;
      const float4 b4 = *(const float4*)(bias + ob);
#pragma unroll
      for (int ns = 0; ns < 2; ++ns) {
        const int n = n0 + wc * 32 + ns * 16 + lr;
        const size_t i0 = ((size_t)b * 256 + ob) * 1024 + n;
        out[i0]          = acc[ms][ns][0] + b4.x + xres[i0];
        out[i0 + 1024]   = acc[ms][ns][1] + b4.y + xres[i0 + 1024];
        out[i0 + 2048]   = acc[ms][ns][2] + b4.z + xres[i0 + 2048];
        out[i0 + 3072]   = acc[ms][ns][3] + b4.w + xres[i0 + 3072];
      }
    }
  }
}

// ---------------------------------------------------------------------------
// Kernel 3: bf16 MFMA flash attention, KVBLK=128, exp2-domain softmax
// (log2e folded into Q pre-scale). Block 256 thr (4 waves x 16 q-rows).
// Grid (16, 64).
// ---------------------------------------------------------------------------
__global__ __launch_bounds__(256) void attn_kernel(
    const ushort* __restrict__ qT, const ushort* __restrict__ kT,
    const ushort* __restrict__ vN, ushort* __restrict__ aoT)
{
  const int t = threadIdx.x;
  const int w = t >> 6, l = t & 63;
  const int lg = l >> 4, lr = l & 15;
  const int bh = blockIdx.y;
  const int b = bh >> 3, hh = bh & 7;
  const int qbase = blockIdx.x << 6;

  __shared__ ushort Ks[128][40];   // [m][d]  pitch 80 B
  __shared__ ushort Vs[32][136];   // [d][m]  pitch 272 B

  union FragU { ushort4 u[2]; bf16x8 f; };

  FragU qf;
  {
    const ushort* Qp = qT + (((size_t)bh * 1024 + qbase + w * 16 + lr) * 32) + lg * 4;
    qf.u[0] = *(const ushort4*)Qp;
    qf.u[1] = *(const ushort4*)(Qp + 16);
  }

  f32x4 accO[2] = {};
  float m_st = -1e30f, l_st = 0.f;

  const ushort* Kbh = kT + (size_t)bh * 1024 * 32;
  const ushort* Vbh = vN + (size_t)bh * 32 * 1024;

  for (int m0 = 0; m0 < NN; m0 += 128) {
    __syncthreads();
    {
      // K tile: 128 m x 32 d = 8 KB contiguous.
      const uint4* kp4 = (const uint4*)(Kbh + (size_t)m0 * 32);
      const uint4 kv0 = kp4[t], kv1 = kp4[t + 256];
      *(uint4*)&Ks[t >> 2][(t & 3) * 8] = kv0;
      *(uint4*)&Ks[64 + (t >> 2)][(t & 3) * 8] = kv1;
      // V tile: 32 d x 128 m.
      const int d = t >> 4, m8 = (t & 15) * 8;
      const uint4 vv0 = *(const uint4*)(Vbh + (size_t)d * 1024 + m0 + m8);
      const uint4 vv1 = *(const uint4*)(Vbh + (size_t)(d + 16) * 1024 + m0 + m8);
      *(uint4*)&Vs[d][m8] = vv0;
      *(uint4*)&Vs[d + 16][m8] = vv1;
    }
    __syncthreads();

    // S^T = K . Q^T : 8 MFMAs, lane column n = lr, values in log2 domain.
    f32x4 s[8];
#pragma unroll
    for (int ms = 0; ms < 8; ++ms) {
      FragU kf;
      const ushort* kp = &Ks[ms * 16 + lr][lg * 4];
      kf.u[0] = *(const ushort4*)kp;
      kf.u[1] = *(const ushort4*)(kp + 16);
      f32x4 z = {0.f, 0.f, 0.f, 0.f};
      s[ms] = __builtin_amdgcn_mfma_f32_16x16x32_bf16(kf.f, qf.f, z, 0, 0, 0);
    }

    float mx = s[0][0];
#pragma unroll
    for (int ms = 0; ms < 8; ++ms)
#pragma unroll
      for (int r = 0; r < 4; ++r) mx = fmaxf(mx, s[ms][r]);
    mx = fmaxf(mx, __shfl_xor(mx, 16));
    mx = fmaxf(mx, __shfl_xor(mx, 32));
    const float mnew = fmaxf(m_st, mx);
    const float c = EXP2(m_st - mnew);
    m_st = mnew;
    float ls = 0.f;
#pragma unroll
    for (int ms = 0; ms < 8; ++ms)
#pragma unroll
      for (int r = 0; r < 4; ++r) {
        const float p = EXP2(s[ms][r] - mnew);
        s[ms][r] = p;
        ls += p;
      }
    ls += __shfl_xor(ls, 16);
    ls += __shfl_xor(ls, 32);
    l_st = l_st * c + ls;
#pragma unroll
    for (int dt = 0; dt < 2; ++dt)
#pragma unroll
      for (int r = 0; r < 4; ++r) accO[dt][r] *= c;

    // P -> bf16 B-fragments (4 m-chunks of 32).
    bf16x8 pb[4];
#pragma unroll
    for (int mc = 0; mc < 4; ++mc) {
      bf16x8 f;
#pragma unroll
      for (int r = 0; r < 4; ++r) {
        f[r]     = (short)f2bf(s[2 * mc][r]);
        f[r + 4] = (short)f2bf(s[2 * mc + 1][r]);
      }
      pb[mc] = f;
    }

    // PV: O^T[d][n] += V[d][m] . P^T[m][n].
#pragma unroll
    for (int dt = 0; dt < 2; ++dt) {
#pragma unroll
      for (int mc = 0; mc < 4; ++mc) {
        FragU vf;
        const ushort* vp = &Vs[dt * 16 + lr][mc * 32 + lg * 4];
        vf.u[0] = *(const ushort4*)vp;
        vf.u[1] = *(const ushort4*)(vp + 16);
        accO[dt] = __builtin_amdgcn_mfma_f32_16x16x32_bf16(vf.f, pb[mc], accO[dt], 0, 0, 0);
      }
    }
  }

  const float inv = 1.f / l_st;
  const int n = qbase + w * 16 + lr;
  ushort* ap = aoT + ((size_t)b * 1024 + n) * 256 + hh * 32 + lg * 4;
#pragma unroll
  for (int dt = 0; dt < 2; ++dt) {
    ushort4 w4;
    w4.x = f2bf(accO[dt][0] * inv);
    w4.y = f2bf(accO[dt][1] * inv);
    w4.z = f2bf(accO[dt][2] * inv);
    w4.w = f2bf(accO[dt][3] * inv);
    *(ushort4*)(ap + dt * 16) = w4;
  }
}

// ---------------------------------------------------------------------------
// Launch. ws layout (MB offsets, bf16):
//   h[b][c][n] @0 | hT[b][n][c] @4 | qT @8 | kT @12 | vN @16 | aoT @20 | wbf @24
// ---------------------------------------------------------------------------
extern "C" void kernel_launch(void* const* d_in, const int* in_sizes, int n_in,
                              void* d_out, int out_size, void* d_ws, size_t ws_size,
                              hipStream_t stream)
{
  const float* x    = (const float*)d_in[0];
  const float* gns  = (const float*)d_in[1];
  const float* gnb  = (const float*)d_in[2];
  const float* wqkv = (const float*)d_in[3];
  const float* bqkv = (const float*)d_in[4];
  const float* wout = (const float*)d_in[5];
  const float* bout = (const float*)d_in[6];
  float* out = (float*)d_out;

  char* ws = (char*)d_ws;
  ushort* h   = (ushort*)(ws);
  ushort* hT  = (ushort*)(ws + (4u << 20));
  ushort* qT  = (ushort*)(ws + (8u << 20));
  ushort* kT  = (ushort*)(ws + (12u << 20));
  ushort* vN  = (ushort*)(ws + (16u << 20));
  ushort* aoT = (ushort*)(ws + (20u << 20));
  ushort* wbf = (ushort*)(ws + (24u << 20));

  wcast_kernel<<<dim3(128), dim3(256), 0, stream>>>(wqkv, wout, wbf);
  gn_kernel<<<dim3(64), dim3(1024), 0, stream>>>(x, gns, gnb, h);
  transpose_kernel<<<dim3(16, 4, 8), dim3(256), 0, stream>>>(h, hT);
  conv_mfma_kernel<0><<<dim3(16, 12, 8), dim3(256), 0, stream>>>(
      wbf, bqkv, hT, nullptr, qT, kT, vN, nullptr);
  attn_kernel<<<dim3(16, 64), dim3(256), 0, stream>>>(qT, kT, vN, aoT);
  conv_mfma_kernel<1><<<dim3(16, 4, 8), dim3(256), 0, stream>>>(
      wbf + 768 * 256, bout, aoT, x, nullptr, nullptr, nullptr, out);
}